// Round 1
// 187.866 us; speedup vs baseline: 1.4110x; 1.4110x over previous
//
#include <hip/hip_runtime.h>
#include <cstddef>

#define BATCH 4
#define CH    16
#define HH    512
#define WW    512
#define HID   128
#define K3    48      // 3*CH
#define YSTR  72      // sY row stride (48 feats + 16 K-pad + 8 bank-pad), 144 B
#define HSTR  136     // sH row stride (128 + 8 bank-pad), 272 B
#define XSTR  17      // sXC row stride in fp32 (odd -> conflict-free)

typedef __bf16 bf16x8 __attribute__((ext_vector_type(8)));
typedef __bf16 bf16x4 __attribute__((ext_vector_type(4)));
typedef float  f32x4  __attribute__((ext_vector_type(4)));

static __device__ __forceinline__ f32x4 mfma16(bf16x8 a, bf16x8 b, f32x4 c) {
    return __builtin_amdgcn_mfma_f32_16x16x32_bf16(a, b, c, 0, 0, 0);
}

// One block per (b, image row); 8 segments of 64 px.
// v4 changes vs v3 (latency attack; MFMA/layout structure unchanged):
//  - ru row preloaded to LDS (kills the per-segment epilogue HBM stall that
//    also force-drained the stencil prefetch via vmcnt ordering)
//  - raw s_barrier + explicit lgkmcnt(0) instead of __syncthreads(): no
//    vmcnt(0) drain at barriers -> stores + prefetched loads stay in flight
//  - depth-2 stencil prefetch (LA/LB ping-pong): issue->use window = one
//    full segment (> HBM latency) instead of ~500 cy
__global__ __launch_bounds__(256, 3)
void ca_mfma4(const float* __restrict__ x, const float* __restrict__ w0,
              const float* __restrict__ b0, const float* __restrict__ w1,
              const float* __restrict__ ru, float* __restrict__ out)
{
    // frag-ordered weights: sW0[ks][t][lane][8], sW1[s][lane][8]
    __shared__ __align__(16) __bf16 sW0[2 * 8 * 64 * 8];   // 16 KB
    __shared__ __align__(16) __bf16 sW1[4 * 64 * 8];       //  4 KB
    __shared__ __align__(16) __bf16 sY[64 * YSTR];         // 9.0 KB
    __shared__ __align__(16) __bf16 sH[64 * HSTR];         // 17.0 KB
    __shared__ float sXC[64 * XSTR];                       // 4.25 KB
    __shared__ float sRU[WW];                              // 2.0 KB  (53.5 KB total, 3 blk/CU)

    const int tid  = threadIdx.x;
    const int lane = tid & 63;
    const int wv   = tid >> 6;
    const int p    = lane & 15;   // MFMA m/n index
    const int q    = lane >> 4;   // quad

    const int row = blockIdx.x;
    const int b   = row >> 9;
    const int i   = row & (HH - 1);

    const size_t plane = (size_t)HH * WW;
    const float* xb    = x + (size_t)b * CH * plane + (size_t)i * WW;
    const bool   up    = (i > 0), dn = (i < HH - 1);
    const int    px    = tid & 63;        // feature-build pixel

    // stencil load buffers (depth-2 ping-pong): [ch 0..3][ul,u,ur, l,m,r, dl,d,dr]
    float LA[4][9], LB[4][9];

    auto issue_loads = [&](int s, float (&L)[4][9]) {
        const int j  = s * 64 + px;
        const bool lf = (j > 0), rt = (j < WW - 1);
        #pragma unroll
        for (int k = 0; k < 4; ++k) {
            const float* c0 = xb + (size_t)(4 * wv + k) * plane + j;
            L[k][0] = (up && lf) ? c0[-WW - 1] : 0.f;
            L[k][1] =  up        ? c0[-WW]     : 0.f;
            L[k][2] = (up && rt) ? c0[-WW + 1] : 0.f;
            L[k][3] =  lf        ? c0[-1]      : 0.f;
            L[k][4] =              c0[0];
            L[k][5] =  rt        ? c0[1]       : 0.f;
            L[k][6] = (dn && lf) ? c0[WW - 1]  : 0.f;
            L[k][7] =  dn        ? c0[WW]      : 0.f;
            L[k][8] = (dn && rt) ? c0[WW + 1]  : 0.f;
        }
    };

    // issue segment-0/1 stencil loads first: they complete under the weight
    // staging + barrier below (free prologue latency hiding)
    issue_loads(0, LA);
    issue_loads(1, LB);

    // ---- stage W0 (+bias at k==48) into LDS, frag-ordered ----
    for (int e = tid; e < 1024; e += 256) {
        const int ks = e >> 9, rem = e & 511;
        const int t = rem >> 6, ln = rem & 63;
        const int pp = ln & 15, qq = ln >> 4;
        const int o = 16 * t + pp;
        bf16x8 v;
        #pragma unroll
        for (int j = 0; j < 8; ++j) {
            const int k = 32 * ks + 8 * qq + j;
            float val;
            if (k < K3)       val = w0[o * K3 + k];
            else if (k == K3) val = b0[o];
            else              val = 0.f;
            v[j] = (__bf16)val;
        }
        *(bf16x8*)&sW0[e * 8] = v;
    }
    // ---- stage W1 [16 x 128] frag-ordered: one entry per thread ----
    {
        const int e = tid;                 // 256 entries total
        const int s = e >> 6, ln = e & 63;
        const int pp = ln & 15, qq = ln >> 4;
        bf16x8 v;
        #pragma unroll
        for (int j = 0; j < 8; ++j)
            v[j] = (__bf16)w1[pp * HID + 32 * s + 8 * qq + j];
        *(bf16x8*)&sW1[e * 8] = v;
    }
    // ---- stage the mask row (512 floats): epilogue reads LDS, not HBM ----
    for (int e = tid; e < WW; e += 256)
        sRU[e] = ru[(size_t)b * plane + (size_t)i * WW + e];
    // ---- static K-pad of sY: feature 48 = 1.0 (bias), 49..63 = 0 ----
    if (tid < 64) {
        bf16x8 z0, z1;
        #pragma unroll
        for (int j = 0; j < 8; ++j) { z0[j] = (__bf16)0.f; z1[j] = (__bf16)0.f; }
        z0[0] = (__bf16)1.0f;
        *(bf16x8*)&sY[tid * YSTR + 48] = z0;
        *(bf16x8*)&sY[tid * YSTR + 56] = z1;
    }
    asm volatile("s_waitcnt lgkmcnt(0)");
    __builtin_amdgcn_s_barrier();

    auto seg_body = [&](int s, float (&L)[4][9]) {
        // ---- compute Sobel features from in-flight loads (VALU only) ----
        float fm[4], fgx[4], fgy[4];
        #pragma unroll
        for (int k = 0; k < 4; ++k) {
            fm[k]  = L[k][4];
            fgx[k] = (L[k][2] - L[k][0]) + 2.f * (L[k][5] - L[k][3]) + (L[k][8] - L[k][6]);
            fgy[k] = (L[k][6] - L[k][0]) + 2.f * (L[k][7] - L[k][1]) + (L[k][8] - L[k][2]);
        }
        // #A: all waves done reading sY/sXC of segment s-1 (their ds_reads
        // were consumed before reaching this barrier; no lgkm fence needed)
        __builtin_amdgcn_s_barrier();
        #pragma unroll
        for (int k = 0; k < 4; ++k) {
            const int ch = 4 * wv + k;
            sY[px * YSTR + ch]          = (__bf16)fm[k];
            sY[px * YSTR + CH + ch]     = (__bf16)fgx[k];
            sY[px * YSTR + 2 * CH + ch] = (__bf16)fgy[k];
            sXC[px * XSTR + ch]         = fm[k];
        }
        // #B: LDS writes visible; NOTE: no vmcnt drain -> prefetched stencil
        // loads and output stores stay in flight across the barrier
        asm volatile("s_waitcnt lgkmcnt(0)");
        __builtin_amdgcn_s_barrier();

        if (s < 6) issue_loads(s + 2, L);   // depth-2: in flight for a full segment

        // ---- MFMA phase: wave wv owns pixels 16*wv .. 16*wv+15 ----
        const int pxg = 16 * wv + p;
        const bf16x8 yb0 = *(const bf16x8*)&sY[pxg * YSTR + 8 * q];
        const bf16x8 yb1 = *(const bf16x8*)&sY[pxg * YSTR + 32 + 8 * q];

        f32x4 acc[8];
        #pragma unroll
        for (int t = 0; t < 8; ++t) {
            const bf16x8 a0 = *(const bf16x8*)&sW0[((0 * 8 + t) * 64 + lane) * 8];
            const bf16x8 a1 = *(const bf16x8*)&sW0[((1 * 8 + t) * 64 + lane) * 8];
            acc[t] = f32x4{0.f, 0.f, 0.f, 0.f};
            acc[t] = mfma16(a0, yb0, acc[t]);
            acc[t] = mfma16(a1, yb1, acc[t]);
        }
        // relu + cvt -> sH[pxg][o], o = 16t + 4q + r (D-layout: col=px, row=4q+r)
        #pragma unroll
        for (int t = 0; t < 8; ++t) {
            bf16x4 hv;
            #pragma unroll
            for (int r = 0; r < 4; ++r)
                hv[r] = (__bf16)fmaxf(acc[t][r], 0.f);
            *(bf16x4*)&sH[pxg * HSTR + 16 * t + 4 * q] = hv;
        }
        // same-wave LDS write->read, wave-private rows: no barrier needed
        f32x4 u = f32x4{0.f, 0.f, 0.f, 0.f};
        #pragma unroll
        for (int ss = 0; ss < 4; ++ss) {
            const bf16x8 hb = *(const bf16x8*)&sH[pxg * HSTR + 32 * ss + 8 * q];
            const bf16x8 aw = *(const bf16x8*)&sW1[(ss * 64 + lane) * 8];
            u = mfma16(aw, hb, u);
        }

        // ---- epilogue: out[c][jg] = xc + u[r]*mask, c = 4q + r ----
        const int jg = s * 64 + pxg;
        const float rv = sRU[jg];          // LDS, not HBM: no vmcnt stall here
        const float m  = (rv > 0.5f) ? 1.f : 0.f;
        float* ob = out + (size_t)b * CH * plane + (size_t)i * WW + jg;
        #pragma unroll
        for (int r = 0; r < 4; ++r) {
            const int c = 4 * q + r;
            ob[(size_t)c * plane] = fmaf(u[r], m, sXC[pxg * XSTR + c]);
        }
    };

    for (int sp = 0; sp < 4; ++sp) {
        seg_body(2 * sp,     LA);
        seg_body(2 * sp + 1, LB);
    }
}

extern "C" void kernel_launch(void* const* d_in, const int* in_sizes, int n_in,
                              void* d_out, int out_size, void* d_ws, size_t ws_size,
                              hipStream_t stream) {
    const float* x  = (const float*)d_in[0];
    const float* w0 = (const float*)d_in[1];
    const float* b0 = (const float*)d_in[2];
    const float* w1 = (const float*)d_in[3];
    const float* ru = (const float*)d_in[4];
    float* out = (float*)d_out;

    dim3 grid(BATCH * HH);   // 2048 blocks: one per (batch, image row)
    dim3 block(256);
    hipLaunchKernelGGL(ca_mfma4, grid, block, 0, stream, x, w0, b0, w1, ru, out);
}